// Round 2
// baseline (674.897 us; speedup 1.0000x reference)
//
#include <hip/hip_runtime.h>
#include <cstdint>
#include <cstddef>

#define BN_EPS 1e-5

// ---------------- reductions (fp64 for exact sign decisions) ----------------

__global__ void zero_d(double* p, int n) {
  int i = blockIdx.x * blockDim.x + threadIdx.x;
  if (i < n) p[i] = 0.0;
}

// one contiguous HW plane per block: grid (C, N)
__global__ void reduce_plane(const float* __restrict__ x, double* __restrict__ sums,
                             int C, int HW) {
  int c = blockIdx.x, n = blockIdx.y;
  const float* p = x + ((long)n * C + c) * HW;
  double s = 0.0, s2 = 0.0;
  for (int i = threadIdx.x; i < HW; i += blockDim.x) {
    double v = (double)p[i];
    s += v; s2 += v * v;
  }
  for (int o = 32; o > 0; o >>= 1) {
    s  += __shfl_down(s, o, 64);
    s2 += __shfl_down(s2, o, 64);
  }
  __shared__ double ls[4], ls2[4];
  int lane = threadIdx.x & 63, w = threadIdx.x >> 6;
  if (lane == 0) { ls[w] = s; ls2[w] = s2; }
  __syncthreads();
  if (threadIdx.x == 0) {
    double a = 0, b = 0;
    for (int i = 0; i < 4; i++) { a += ls[i]; b += ls2[i]; }
    atomicAdd(&sums[2 * c], a);
    atomicAdd(&sums[2 * c + 1], b);
  }
}

// channel-last reduce: x [rows][C]; grid (C/64, RB), block 256 (4 waves).
__global__ void reduce_cl(const float* __restrict__ x, double* __restrict__ sums,
                          int C, long rows) {
  int lane = threadIdx.x & 63, wv = threadIdx.x >> 6;
  int c = blockIdx.x * 64 + lane;
  double s = 0.0, s2 = 0.0;
  for (long r = blockIdx.y * 4 + wv; r < rows; r += (long)gridDim.y * 4) {
    double v = (double)x[r * C + c];
    s += v; s2 += v * v;
  }
  __shared__ double ls[4][64], ls2[4][64];
  ls[wv][lane] = s; ls2[wv][lane] = s2;
  __syncthreads();
  if (threadIdx.x < 64) {
    double a = ls[0][lane] + ls[1][lane] + ls[2][lane] + ls[3][lane];
    double b = ls2[0][lane] + ls2[1][lane] + ls2[2][lane] + ls2[3][lane];
    atomicAdd(&sums[2 * c], a);
    atomicAdd(&sums[2 * c + 1], b);
  }
}

// row-split per-feature reduce of R x F (F % 256 == 0); grid (F/256, RB).
__global__ void reduce_cols2(const float* __restrict__ x, double* __restrict__ sums,
                             int R, int F, int RS) {
  int f = blockIdx.x * blockDim.x + threadIdx.x;
  int r0 = blockIdx.y * RS, r1 = min(r0 + RS, R);
  double s = 0.0, s2 = 0.0;
  for (int r = r0; r < r1; r++) {
    double v = (double)x[(long)r * F + f];
    s += v; s2 += v * v;
  }
  atomicAdd(&sums[2 * f], s);
  atomicAdd(&sums[2 * f + 1], s2);
}

__global__ void finalize_stats(const double* __restrict__ sums, double2* __restrict__ st,
                               int C, double cnt) {
  int c = blockIdx.x * blockDim.x + threadIdx.x;
  if (c >= C) return;
  double m = sums[2 * c] / cnt;
  double v = sums[2 * c + 1] / cnt - m * m;
  st[c] = make_double2(m, 1.0 / sqrt(v + BN_EPS));
}

// ---------------- ballot-based sign/pack kernels ----------------

__global__ void pack_bits_c1(const float* __restrict__ x, const double2* __restrict__ st,
                             const float* __restrict__ g, const float* __restrict__ b,
                             uint64_t* __restrict__ rows) {
  int wid = blockIdx.x * 4 + (threadIdx.x >> 6);
  int lane = threadIdx.x & 63;
  int n = wid / 192, rem = wid % 192;
  int ci = rem >> 6, y = rem & 63;
  double2 s = st[ci];
  float xv = x[(((long)n * 3 + ci) * 64 + y) * 64 + lane];
  float xn = (float)(((double)xv - s.x) * s.y) * g[ci] + b[ci];
  uint64_t m = __ballot(xn > 0.f);
  if (lane == 0) rows[wid] = m;
}

__global__ void pack_wc1(const float* __restrict__ w, uint32_t* __restrict__ wm) {
  int co = threadIdx.x;
  uint32_t m = 0;
  for (int j = 0; j < 27; j++) m |= (uint32_t)(w[co * 27 + j] > 0.f) << j;
  wm[co] = m;
}

__global__ void pack_cl(const float* __restrict__ acl, const double2* __restrict__ st,
                        const float* __restrict__ g, const float* __restrict__ b,
                        uint64_t* __restrict__ out, int C, long nwords, int lw) {
  long wid = (long)blockIdx.x * 4 + (threadIdx.x >> 6);
  if (wid >= nwords) return;
  int lane = threadIdx.x & 63;
  long row = wid >> lw;
  int w = (int)(wid & ((1 << lw) - 1));
  int c = w * 64 + lane;
  double2 s = st[c];
  float xv = acl[row * C + c];
  float xn = (float)(((double)xv - s.x) * s.y) * g[c] + b[c];
  uint64_t m = __ballot(xn > 0.f);
  if (lane == 0) out[wid] = m;
}

__global__ void pack_wconv(const float* __restrict__ w, uint64_t* __restrict__ out,
                           int CO, int CI, int W) {
  int i = blockIdx.x * blockDim.x + threadIdx.x;
  int total = CO * 9 * W;
  if (i >= total) return;
  int wd = i % W;
  int t = i / W;
  int tap = t % 9, co = t / 9;
  uint64_t bits = 0;
  for (int k = 0; k < 64; k++) {
    int ci = wd * 64 + k;
    bits |= (uint64_t)(w[((long)co * CI + ci) * 9 + tap] > 0.f) << k;
  }
  out[i] = bits;
}

// pack sign/nonzero masks AND accumulate per-row nonzero count (exact in fp64)
__global__ void pack_nz(const float* __restrict__ x, const double2* __restrict__ st,
                        const float* __restrict__ g, const float* __restrict__ b,
                        uint64_t* __restrict__ out, double* __restrict__ nzc,
                        int R, int F) {
  int Wf = F >> 6;
  long wid = (long)blockIdx.x * 4 + (threadIdx.x >> 6);
  if (wid >= (long)R * Wf) return;
  int lane = threadIdx.x & 63;
  long r = wid / Wf;
  int w = (int)(wid % Wf);
  int f = w * 64 + lane;
  double2 s = st[f];
  double d = (double)x[r * F + f] - s.x;  // exact for lattice values
  float xn = (float)(d * s.y) * g[f] + b[f];
  uint64_t sm = __ballot(xn > 0.f);
  uint64_t nm = __ballot(d != 0.0);
  if (lane == 0) {
    out[2 * wid] = sm; out[2 * wid + 1] = nm;
    atomicAdd(&nzc[r], (double)__popcll(nm));
  }
}

// transposed weight pack: out [wd][O] so fc weight loads are lane-coalesced
__global__ void pack_wfc2_t(const float* __restrict__ w, uint64_t* __restrict__ out,
                            int O, int F) {
  int Wf = F >> 6;
  long wid = (long)blockIdx.x * 4 + (threadIdx.x >> 6);
  if (wid >= (long)O * Wf) return;
  int lane = threadIdx.x & 63;
  long o = wid / Wf;
  int wd = (int)(wid % Wf);
  uint64_t m = __ballot(w[o * F + wd * 64 + lane] > 0.f);
  if (lane == 0) out[(long)wd * O + o] = m;
}

// ---------------- fused conv + maxpool + prelu ----------------

// conv1 via 27-bit xnor-popcount; out channel-last [n][961][128]
__global__ __launch_bounds__(256) void conv1_pool3(const uint64_t* __restrict__ rows,
                                                   const uint32_t* __restrict__ wm,
                                                   const float* __restrict__ cp,
                                                   float* __restrict__ out) {
  __shared__ uint64_t rL[192];
  __shared__ uint32_t wL[128];
  __shared__ uint32_t mL[61 * 4];
  int n = blockIdx.y, chunk = blockIdx.x, t = threadIdx.x;
  if (t < 192) rL[t] = rows[n * 192 + t];
  if (t < 128) wL[t] = wm[t];
  __syncthreads();
  if (t < 244) {
    int pl = t >> 2, quad = t & 3;
    int pos = chunk * 61 + pl;
    if (pos < 961) {
      int py = pos / 31, px = pos - py * 31;
      int cy = 2 * py + (quad >> 1), cx = 2 * px + (quad & 1);
      uint32_t m = 0;
#pragma unroll
      for (int ci = 0; ci < 3; ci++)
#pragma unroll
        for (int ky = 0; ky < 3; ky++)
          m |= (uint32_t)((rL[ci * 64 + cy + ky] >> cx) & 7) << (ci * 9 + ky * 3);
      mL[pl * 4 + quad] = m;
    }
  }
  __syncthreads();
  int co = t & 127, slot = t >> 7;
  float alpha = cp[0];
  uint32_t w = wL[co];
  for (int i = slot; i < 61; i += 2) {
    int pos = chunk * 61 + i;
    if (pos >= 961) break;
    int p0 = __popc(mL[4 * i] ^ w);
    int p1 = __popc(mL[4 * i + 1] ^ w);
    int p2 = __popc(mL[4 * i + 2] ^ w);
    int p3 = __popc(mL[4 * i + 3] ^ w);
    int dot = 27 - 2 * min(min(p0, p1), min(p2, p3));
    float f = (float)dot;
    out[((long)n * 961 + pos) * 128 + co] = dot >= 0 ? f : alpha * f;
  }
}

// Word-streaming xnor conv + pool + prelu: one wave per (co-group, py).
// Input window words are read from LDS as WAVE-UNIFORM broadcasts (same
// address in all lanes -> conflict-free, immediate offsets after full unroll)
// and used immediately for their <=4 pool-quadrant taps — NO register window
// arrays. R1 evidence: with hA/hB+wr arrays the allocator parked them in
// AGPRs (ArchVGPR=68, total ~256 -> occupancy pinned at 2 waves/EU) and paid
// v_accvgpr_read on every use = ~2.2x VALU issue. Streaming keeps the live
// set at wr(18W regs)+word+4 accs, which fits arch VGPRs cleanly.
// in [n][IH][IH][W], wt [co][9W], out CL? [n][PH*PH][CO] : [n][CO][PH*PH].
// Each block stages 10 input rows (rows 8*chunk .. 8*chunk+9).
template <int W, int IH, int PH, int CHUNK, bool CL>
__global__ __attribute__((amdgpu_flat_work_group_size(256, 256),
                          amdgpu_waves_per_eu(2, 4)))
void convp_stream(const uint64_t* __restrict__ in, const uint64_t* __restrict__ wt,
                  const float* __restrict__ cp, float* __restrict__ out, int CO) {
  __shared__ uint64_t sIn[10 * IH * W];
  int n = blockIdx.y;
  int cg = blockIdx.x / CHUNK, chunk = blockIdx.x % CHUNK;
  int t = threadIdx.x, lane = t & 63, slot = t >> 6;
  int r0 = chunk * 8;
  int nr = min(10, IH - r0);
  const uint64_t* src = in + ((long)n * IH + r0) * (IH * W);
  for (int i = t; i < nr * IH * W; i += 256) sIn[i] = src[i];
  int co = cg * 64 + lane;
  uint64_t wr[9 * W];
  const uint64_t* wg = wt + (long)co * (9 * W);
#pragma unroll
  for (int i = 0; i < 9 * W; i++) wr[i] = wg[i];
  __syncthreads();
  int py = chunk * 4 + slot;
  if (py >= PH) return;
  float alpha = cp[0];
  const int K = 9 * 64 * W;
  const uint64_t* base = &sIn[(2 * slot) * (IH * W)];  // local row = 2*slot+cy
#pragma unroll
  for (int px = 0; px < PH; px++) {
    int a00 = 0, a01 = 0, a10 = 0, a11 = 0;
#pragma unroll
    for (int cy = 0; cy < 4; cy++) {
#pragma unroll
      for (int col = 0; col < 4; col++) {
#pragma unroll
        for (int wd = 0; wd < W; wd++) {
          uint64_t v = base[(cy * IH + 2 * px + col) * W + wd];
#pragma unroll
          for (int dy = 0; dy < 2; dy++) {
            int ky = cy - dy;
            if (ky < 0 || ky > 2) continue;  // compile-time folded
#pragma unroll
            for (int dx = 0; dx < 2; dx++) {
              int kx = col - dx;
              if (kx < 0 || kx > 2) continue;  // compile-time folded
              int p = __popcll(v ^ wr[(ky * 3 + kx) * W + wd]);
              if (dy == 0) { if (dx == 0) a00 += p; else a01 += p; }
              else         { if (dx == 0) a10 += p; else a11 += p; }
            }
          }
        }
      }
    }
    int dot = K - 2 * min(min(a00, a01), min(a10, a11));
    float f = (float)dot;
    long idx = CL ? (((long)n * PH * PH + py * PH + px) * CO + co)
                  : (((long)n * CO + co) * PH * PH + (py * PH + px));
    out[idx] = dot >= 0 ? f : alpha * f;
  }
}

// ---------------- binary fc (with nonzero mask on activations) ----------------

// 4 rows per block; weights transposed [wd][O] -> lane-coalesced 512B loads,
// reused x4 in registers; per-row nzc precomputed by pack_nz.
__global__ void fc_bin4(const uint64_t* __restrict__ xp, const uint64_t* __restrict__ wp_t,
                        const double* __restrict__ nzc, const float* __restrict__ cp,
                        float* __restrict__ out, int O, int Wf) {
  __shared__ uint64_t xs[4][288], xz[4][288];
  int r0 = blockIdx.y * 4;
  for (int i = threadIdx.x; i < 4 * Wf; i += blockDim.x) {
    int rr = i / Wf, wd = i - rr * Wf;
    xs[rr][wd] = xp[(((long)(r0 + rr)) * Wf + wd) * 2];
    xz[rr][wd] = xp[(((long)(r0 + rr)) * Wf + wd) * 2 + 1];
  }
  __syncthreads();
  int o = blockIdx.x * blockDim.x + threadIdx.x;
  if (o >= O) return;
  int pc0 = 0, pc1 = 0, pc2 = 0, pc3 = 0;
  for (int wd = 0; wd < Wf; wd++) {
    uint64_t w = wp_t[(long)wd * O + o];
    pc0 += __popcll((xs[0][wd] ^ w) & xz[0][wd]);
    pc1 += __popcll((xs[1][wd] ^ w) & xz[1][wd]);
    pc2 += __popcll((xs[2][wd] ^ w) & xz[2][wd]);
    pc3 += __popcll((xs[3][wd] ^ w) & xz[3][wd]);
  }
  float alpha = cp[0];
  int dots[4] = {pc0, pc1, pc2, pc3};
#pragma unroll
  for (int rr = 0; rr < 4; rr++) {
    int dot = (int)nzc[r0 + rr] - 2 * dots[rr];
    float f = (float)dot;
    out[(long)(r0 + rr) * O + o] = dot >= 0 ? f : alpha * f;
  }
}

__global__ void fc_bin_scale(const uint64_t* __restrict__ xp, const uint64_t* __restrict__ wp_t,
                             const double* __restrict__ nzc, const float* __restrict__ cp,
                             const float* __restrict__ scale, float* __restrict__ out,
                             int R, int O, int Wf) {
  int i = blockIdx.x * blockDim.x + threadIdx.x;
  if (i >= R * O) return;
  int o = i % O, r = i / O;
  int pc = 0;
  for (int wd = 0; wd < Wf; wd++) {
    uint64_t nz = xp[((long)r * Wf + wd) * 2 + 1];
    pc += __popcll((xp[((long)r * Wf + wd) * 2] ^ wp_t[(long)wd * O + o]) & nz);
  }
  int dot = (int)nzc[r] - 2 * pc;
  float f = (float)dot;
  float alpha = cp[0];
  f = dot >= 0 ? f : alpha * f;
  out[i] = f * scale[0];
}

// ---------------- launch ----------------

extern "C" void kernel_launch(void* const* d_in, const int* in_sizes, int n_in,
                              void* d_out, int out_size, void* d_ws, size_t ws_size,
                              hipStream_t stream) {
  const float* x   = (const float*)d_in[0];
  const float* cg0 = (const float*)d_in[1];
  const float* cb0 = (const float*)d_in[2];
  const float* cw0 = (const float*)d_in[3];
  const float* cp0 = (const float*)d_in[4];
  const float* cg1 = (const float*)d_in[5];
  const float* cb1 = (const float*)d_in[6];
  const float* cw1 = (const float*)d_in[7];
  const float* cp1 = (const float*)d_in[8];
  const float* cg2 = (const float*)d_in[9];
  const float* cb2 = (const float*)d_in[10];
  const float* cw2 = (const float*)d_in[11];
  const float* cp2 = (const float*)d_in[12];
  const float* fg0 = (const float*)d_in[13];
  const float* fb0 = (const float*)d_in[14];
  const float* fw0 = (const float*)d_in[15];
  const float* fp0 = (const float*)d_in[16];
  const float* fg1 = (const float*)d_in[17];
  const float* fb1 = (const float*)d_in[18];
  const float* fw1 = (const float*)d_in[19];
  const float* fp1 = (const float*)d_in[20];
  const float* scl = (const float*)d_in[21];

  char* ws = (char*)d_ws;
  size_t off = 0;
  auto alloc = [&](size_t bytes) {
    size_t r = off;
    off += (bytes + 255) & ~(size_t)255;
    return r;
  };
  const int C0_OFF = 0, C1_OFF = 16, C2_OFF = 160, C3_OFF = 448, C4_OFF = 18944;
  const int NCH = 19968;

  // sums, nzcA, nzcB are contiguous (each region 256B-aligned multiple) so a
  // single zero_d call covers all three atomic regions.
  double*   sums  = (double*)(ws + alloc((size_t)NCH * 2 * sizeof(double)));
  double*   nzcA  = (double*)(ws + alloc(128 * sizeof(double)));
  double*   nzcB  = (double*)(ws + alloc(128 * sizeof(double)));
  double2*  stats = (double2*)(ws + alloc((size_t)NCH * sizeof(double2)));
  uint64_t* rows0 = (uint64_t*)(ws + alloc(128L * 3 * 64 * 8));
  uint32_t* wm1   = (uint32_t*)(ws + alloc(128L * 4));
  float*    a1    = (float*)(ws + alloc(128L * 961 * 128 * 4));   // channel-last
  uint64_t* s1p   = (uint64_t*)(ws + alloc(128L * 961 * 2 * 8));
  uint64_t* w1p   = (uint64_t*)(ws + alloc(256L * 9 * 2 * 8));
  float*    a2    = (float*)(ws + alloc(128L * 196 * 256 * 4));   // channel-last
  uint64_t* s2p   = (uint64_t*)(ws + alloc(128L * 196 * 4 * 8));
  uint64_t* w2p   = (uint64_t*)(ws + alloc(512L * 9 * 4 * 8));
  float*    a3    = (float*)(ws + alloc(128L * 512 * 36 * 4));    // channel-major (reshape order)
  uint64_t* s3p   = (uint64_t*)(ws + alloc(128L * 288 * 2 * 8));
  uint64_t* w3p   = (uint64_t*)(ws + alloc(1024L * 288 * 8));     // transposed [288][1024]
  float*    f1    = (float*)(ws + alloc(128L * 1024 * 4));
  uint64_t* s4p   = (uint64_t*)(ws + alloc(128L * 16 * 2 * 8));
  uint64_t* w4p   = (uint64_t*)(ws + alloc(10L * 16 * 8));        // transposed [16][10]

  const int B = 256;

  zero_d<<<dim3(157), B, 0, stream>>>(sums, NCH * 2 + 256);  // sums + nzcA + nzcB

  // ---- block 0: BN(x) -> sign-bits -> conv1(popcount) -> pool -> prelu ----
  reduce_plane<<<dim3(3, 128), B, 0, stream>>>(x, sums + 2 * C0_OFF, 3, 4096);
  finalize_stats<<<1, 64, 0, stream>>>(sums + 2 * C0_OFF, stats + C0_OFF, 3, 524288.0);
  pack_bits_c1<<<dim3(6144), B, 0, stream>>>(x, stats + C0_OFF, cg0, cb0, rows0);
  pack_wc1<<<1, 128, 0, stream>>>(cw0, wm1);
  conv1_pool3<<<dim3(16, 128), B, 0, stream>>>(rows0, wm1, cp0, a1);

  // ---- block 1: BN(a1) -> pack -> conv2 -> pool -> prelu ----
  reduce_cl<<<dim3(2, 256), B, 0, stream>>>(a1, sums + 2 * C1_OFF, 128, 123008L);
  finalize_stats<<<1, 128, 0, stream>>>(sums + 2 * C1_OFF, stats + C1_OFF, 128, 123008.0);
  pack_cl<<<dim3(61504), B, 0, stream>>>(a1, stats + C1_OFF, cg1, cb1, s1p, 128, 246016L, 1);
  pack_wconv<<<dim3(18), B, 0, stream>>>(cw1, w1p, 256, 128, 2);
  // 4 co-groups x 4 py-chunks
  convp_stream<2, 31, 14, 4, true><<<dim3(16, 128), B, 0, stream>>>(s1p, w1p, cp1, a2, 256);

  // ---- block 2: BN(a2) -> pack -> conv3 -> pool -> prelu ----
  reduce_cl<<<dim3(4, 128), B, 0, stream>>>(a2, sums + 2 * C2_OFF, 256, 25088L);
  finalize_stats<<<1, 256, 0, stream>>>(sums + 2 * C2_OFF, stats + C2_OFF, 256, 25088.0);
  pack_cl<<<dim3(25088), B, 0, stream>>>(a2, stats + C2_OFF, cg2, cb2, s2p, 256, 100352L, 2);
  pack_wconv<<<dim3(72), B, 0, stream>>>(cw2, w2p, 512, 256, 4);
  // 8 co-groups x 2 py-chunks
  convp_stream<4, 14, 6, 2, false><<<dim3(16, 128), B, 0, stream>>>(s2p, w2p, cp2, a3, 512);

  // ---- fc 0: BN1d -> sign @ sign(W).T -> prelu ----
  reduce_cols2<<<dim3(72, 8), B, 0, stream>>>(a3, sums + 2 * C3_OFF, 128, 18432, 16);
  finalize_stats<<<dim3(72), B, 0, stream>>>(sums + 2 * C3_OFF, stats + C3_OFF, 18432, 128.0);
  pack_nz<<<dim3(9216), B, 0, stream>>>(a3, stats + C3_OFF, fg0, fb0, s3p, nzcA, 128, 18432);
  pack_wfc2_t<<<dim3(73728), B, 0, stream>>>(fw0, w3p, 1024, 18432);
  fc_bin4<<<dim3(4, 32), B, 0, stream>>>(s3p, w3p, nzcA, fp0, f1, 1024, 288);

  // ---- fc 1: BN1d -> sign @ sign(W).T -> prelu -> scale ----
  reduce_cols2<<<dim3(4, 8), B, 0, stream>>>(f1, sums + 2 * C4_OFF, 128, 1024, 16);
  finalize_stats<<<dim3(4), B, 0, stream>>>(sums + 2 * C4_OFF, stats + C4_OFF, 1024, 128.0);
  pack_nz<<<dim3(512), B, 0, stream>>>(f1, stats + C4_OFF, fg1, fb1, s4p, nzcB, 128, 1024);
  pack_wfc2_t<<<dim3(40), B, 0, stream>>>(fw1, w4p, 10, 1024);
  fc_bin_scale<<<dim3(5), B, 0, stream>>>(s4p, w4p, nzcB, fp1, scl, (float*)d_out, 128, 10, 16);
}

// Round 3
// 673.318 us; speedup vs baseline: 1.0023x; 1.0023x over previous
//
#include <hip/hip_runtime.h>
#include <cstdint>
#include <cstddef>

#define BN_EPS 1e-5

// ---------------- reductions (fp64 for exact sign decisions) ----------------

__global__ void zero_d(double* p, int n) {
  int i = blockIdx.x * blockDim.x + threadIdx.x;
  if (i < n) p[i] = 0.0;
}

// one contiguous HW plane per block: grid (C, N)
__global__ void reduce_plane(const float* __restrict__ x, double* __restrict__ sums,
                             int C, int HW) {
  int c = blockIdx.x, n = blockIdx.y;
  const float* p = x + ((long)n * C + c) * HW;
  double s = 0.0, s2 = 0.0;
  for (int i = threadIdx.x; i < HW; i += blockDim.x) {
    double v = (double)p[i];
    s += v; s2 += v * v;
  }
  for (int o = 32; o > 0; o >>= 1) {
    s  += __shfl_down(s, o, 64);
    s2 += __shfl_down(s2, o, 64);
  }
  __shared__ double ls[4], ls2[4];
  int lane = threadIdx.x & 63, w = threadIdx.x >> 6;
  if (lane == 0) { ls[w] = s; ls2[w] = s2; }
  __syncthreads();
  if (threadIdx.x == 0) {
    double a = 0, b = 0;
    for (int i = 0; i < 4; i++) { a += ls[i]; b += ls2[i]; }
    atomicAdd(&sums[2 * c], a);
    atomicAdd(&sums[2 * c + 1], b);
  }
}

// channel-last reduce: x [rows][C]; grid (C/64, RB), block 256 (4 waves).
__global__ void reduce_cl(const float* __restrict__ x, double* __restrict__ sums,
                          int C, long rows) {
  int lane = threadIdx.x & 63, wv = threadIdx.x >> 6;
  int c = blockIdx.x * 64 + lane;
  double s = 0.0, s2 = 0.0;
  for (long r = blockIdx.y * 4 + wv; r < rows; r += (long)gridDim.y * 4) {
    double v = (double)x[r * C + c];
    s += v; s2 += v * v;
  }
  __shared__ double ls[4][64], ls2[4][64];
  ls[wv][lane] = s; ls2[wv][lane] = s2;
  __syncthreads();
  if (threadIdx.x < 64) {
    double a = ls[0][lane] + ls[1][lane] + ls[2][lane] + ls[3][lane];
    double b = ls2[0][lane] + ls2[1][lane] + ls2[2][lane] + ls2[3][lane];
    atomicAdd(&sums[2 * c], a);
    atomicAdd(&sums[2 * c + 1], b);
  }
}

// row-split per-feature reduce of R x F (F % 256 == 0); grid (F/256, RB).
__global__ void reduce_cols2(const float* __restrict__ x, double* __restrict__ sums,
                             int R, int F, int RS) {
  int f = blockIdx.x * blockDim.x + threadIdx.x;
  int r0 = blockIdx.y * RS, r1 = min(r0 + RS, R);
  double s = 0.0, s2 = 0.0;
  for (int r = r0; r < r1; r++) {
    double v = (double)x[(long)r * F + f];
    s += v; s2 += v * v;
  }
  atomicAdd(&sums[2 * f], s);
  atomicAdd(&sums[2 * f + 1], s2);
}

__global__ void finalize_stats(const double* __restrict__ sums, double2* __restrict__ st,
                               int C, double cnt) {
  int c = blockIdx.x * blockDim.x + threadIdx.x;
  if (c >= C) return;
  double m = sums[2 * c] / cnt;
  double v = sums[2 * c + 1] / cnt - m * m;
  st[c] = make_double2(m, 1.0 / sqrt(v + BN_EPS));
}

// ---------------- ballot-based sign/pack kernels ----------------

__global__ void pack_bits_c1(const float* __restrict__ x, const double2* __restrict__ st,
                             const float* __restrict__ g, const float* __restrict__ b,
                             uint64_t* __restrict__ rows) {
  int wid = blockIdx.x * 4 + (threadIdx.x >> 6);
  int lane = threadIdx.x & 63;
  int n = wid / 192, rem = wid % 192;
  int ci = rem >> 6, y = rem & 63;
  double2 s = st[ci];
  float xv = x[(((long)n * 3 + ci) * 64 + y) * 64 + lane];
  float xn = (float)(((double)xv - s.x) * s.y) * g[ci] + b[ci];
  uint64_t m = __ballot(xn > 0.f);
  if (lane == 0) rows[wid] = m;
}

__global__ void pack_wc1(const float* __restrict__ w, uint32_t* __restrict__ wm) {
  int co = threadIdx.x;
  uint32_t m = 0;
  for (int j = 0; j < 27; j++) m |= (uint32_t)(w[co * 27 + j] > 0.f) << j;
  wm[co] = m;
}

__global__ void pack_cl(const float* __restrict__ acl, const double2* __restrict__ st,
                        const float* __restrict__ g, const float* __restrict__ b,
                        uint64_t* __restrict__ out, int C, long nwords, int lw) {
  long wid = (long)blockIdx.x * 4 + (threadIdx.x >> 6);
  if (wid >= nwords) return;
  int lane = threadIdx.x & 63;
  long row = wid >> lw;
  int w = (int)(wid & ((1 << lw) - 1));
  int c = w * 64 + lane;
  double2 s = st[c];
  float xv = acl[row * C + c];
  float xn = (float)(((double)xv - s.x) * s.y) * g[c] + b[c];
  uint64_t m = __ballot(xn > 0.f);
  if (lane == 0) out[wid] = m;
}

__global__ void pack_wconv(const float* __restrict__ w, uint64_t* __restrict__ out,
                           int CO, int CI, int W) {
  int i = blockIdx.x * blockDim.x + threadIdx.x;
  int total = CO * 9 * W;
  if (i >= total) return;
  int wd = i % W;
  int t = i / W;
  int tap = t % 9, co = t / 9;
  uint64_t bits = 0;
  for (int k = 0; k < 64; k++) {
    int ci = wd * 64 + k;
    bits |= (uint64_t)(w[((long)co * CI + ci) * 9 + tap] > 0.f) << k;
  }
  out[i] = bits;
}

// pack sign + nonzero masks. NO per-row atomic: R2 showed 288-way fp64
// same-address atomic contention serialized this kernel to 93us (VALUBusy
// 3.5%). nzc is recomputed inline by the fc kernels (2 popcll/word, cheap).
__global__ void pack_nz(const float* __restrict__ x, const double2* __restrict__ st,
                        const float* __restrict__ g, const float* __restrict__ b,
                        uint64_t* __restrict__ out, int R, int F) {
  int Wf = F >> 6;
  long wid = (long)blockIdx.x * 4 + (threadIdx.x >> 6);
  if (wid >= (long)R * Wf) return;
  int lane = threadIdx.x & 63;
  long r = wid / Wf;
  int w = (int)(wid % Wf);
  int f = w * 64 + lane;
  double2 s = st[f];
  double d = (double)x[r * F + f] - s.x;  // exact for lattice values
  float xn = (float)(d * s.y) * g[f] + b[f];
  uint64_t sm = __ballot(xn > 0.f);
  uint64_t nm = __ballot(d != 0.0);
  if (lane == 0) { out[2 * wid] = sm; out[2 * wid + 1] = nm; }
}

// transposed weight pack: out [wd][O] so fc weight loads are lane-coalesced
__global__ void pack_wfc2_t(const float* __restrict__ w, uint64_t* __restrict__ out,
                            int O, int F) {
  int Wf = F >> 6;
  long wid = (long)blockIdx.x * 4 + (threadIdx.x >> 6);
  if (wid >= (long)O * Wf) return;
  int lane = threadIdx.x & 63;
  long o = wid / Wf;
  int wd = (int)(wid % Wf);
  uint64_t m = __ballot(w[o * F + wd * 64 + lane] > 0.f);
  if (lane == 0) out[(long)wd * O + o] = m;
}

// ---------------- fused conv + maxpool + prelu ----------------

// conv1 via 27-bit xnor-popcount; out channel-last [n][961][128]
__global__ __launch_bounds__(256) void conv1_pool3(const uint64_t* __restrict__ rows,
                                                   const uint32_t* __restrict__ wm,
                                                   const float* __restrict__ cp,
                                                   float* __restrict__ out) {
  __shared__ uint64_t rL[192];
  __shared__ uint32_t wL[128];
  __shared__ uint32_t mL[61 * 4];
  int n = blockIdx.y, chunk = blockIdx.x, t = threadIdx.x;
  if (t < 192) rL[t] = rows[n * 192 + t];
  if (t < 128) wL[t] = wm[t];
  __syncthreads();
  if (t < 244) {
    int pl = t >> 2, quad = t & 3;
    int pos = chunk * 61 + pl;
    if (pos < 961) {
      int py = pos / 31, px = pos - py * 31;
      int cy = 2 * py + (quad >> 1), cx = 2 * px + (quad & 1);
      uint32_t m = 0;
#pragma unroll
      for (int ci = 0; ci < 3; ci++)
#pragma unroll
        for (int ky = 0; ky < 3; ky++)
          m |= (uint32_t)((rL[ci * 64 + cy + ky] >> cx) & 7) << (ci * 9 + ky * 3);
      mL[pl * 4 + quad] = m;
    }
  }
  __syncthreads();
  int co = t & 127, slot = t >> 7;
  float alpha = cp[0];
  uint32_t w = wL[co];
  for (int i = slot; i < 61; i += 2) {
    int pos = chunk * 61 + i;
    if (pos >= 961) break;
    int p0 = __popc(mL[4 * i] ^ w);
    int p1 = __popc(mL[4 * i + 1] ^ w);
    int p2 = __popc(mL[4 * i + 2] ^ w);
    int p3 = __popc(mL[4 * i + 3] ^ w);
    int dot = 27 - 2 * min(min(p0, p1), min(p2, p3));
    float f = (float)dot;
    out[((long)n * 961 + pos) * 128 + co] = dot >= 0 ? f : alpha * f;
  }
}

// 2-column-carry xnor conv + pool + prelu (conv2, W=2): one wave per
// (co-group, py). Per pooled px, cols 2px,2px+1 are CARRIED in registers from
// the previous px; only cols 2px+2,2px+3 are read from LDS (2W u64
// contiguous -> ds_read_b128 pairs). LDS budget: (PH+1)*8W u64/wave = 120
// b128 -> ~43k LDS cyc/CU < 64.5k VALU cyc/CU => VALU-bound (R2's per-word
// streaming was 448 b64/wave => LDS-pipe-bound). Live set ~90 VGPR (wr 36 +
// carry 32 + fresh 8 + accs) against the 170-reg budget of waves_per_eu(3,4):
// big slack so the allocator neither spills to AGPR (R1 failure) nor remats
// LDS reads.
// in [n][IH][IH][W], wt [co][9W], out CL [n][PH*PH][CO].
template <int W, int IH, int PH, int CHUNK, bool CL>
__global__ __attribute__((amdgpu_flat_work_group_size(256, 256),
                          amdgpu_waves_per_eu(3, 4)))
void convp_carry(const uint64_t* __restrict__ in, const uint64_t* __restrict__ wt,
                 const float* __restrict__ cp, float* __restrict__ out, int CO) {
  __shared__ uint64_t sIn[10 * IH * W];
  int n = blockIdx.y;
  int cg = blockIdx.x / CHUNK, chunk = blockIdx.x % CHUNK;
  int t = threadIdx.x, lane = t & 63, slot = t >> 6;
  int r0 = chunk * 8;
  int nr = min(10, IH - r0);
  const uint64_t* src = in + ((long)n * IH + r0) * (IH * W);
  for (int i = t; i < nr * IH * W; i += 256) sIn[i] = src[i];
  int co = cg * 64 + lane;
  uint64_t wr[9 * W];
  const uint64_t* wg = wt + (long)co * (9 * W);
#pragma unroll
  for (int i = 0; i < 9 * W; i++) wr[i] = wg[i];
  __syncthreads();
  int py = chunk * 4 + slot;
  if (py >= PH) return;
  float alpha = cp[0];
  const int K = 9 * 64 * W;
  const uint64_t* base = &sIn[(2 * slot) * (IH * W)];  // local row = 2*slot+cy
  // carry: cols (2px, 2px+1) for each of the 4 window rows
  uint64_t c[4][2 * W];
#pragma unroll
  for (int cy = 0; cy < 4; cy++) {
    const uint64_t* p = &base[(cy * IH) * W];
#pragma unroll
    for (int j = 0; j < 2 * W; j++) c[cy][j] = p[j];
  }
#pragma unroll
  for (int px = 0; px < PH; px++) {
    int a00 = 0, a01 = 0, a10 = 0, a11 = 0;
#pragma unroll
    for (int cy = 0; cy < 4; cy++) {
      uint64_t f[2 * W];
      const uint64_t* fp = &base[(cy * IH + 2 * px + 2) * W];
#pragma unroll
      for (int j = 0; j < 2 * W; j++) f[j] = fp[j];
#pragma unroll
      for (int col = 0; col < 4; col++) {
#pragma unroll
        for (int wd = 0; wd < W; wd++) {
          uint64_t v = (col < 2) ? c[cy][col * W + wd] : f[(col - 2) * W + wd];
#pragma unroll
          for (int dy = 0; dy < 2; dy++) {
            int ky = cy - dy;
            if (ky < 0 || ky > 2) continue;  // compile-time folded
#pragma unroll
            for (int dx = 0; dx < 2; dx++) {
              int kx = col - dx;
              if (kx < 0 || kx > 2) continue;  // compile-time folded
              int p = __popcll(v ^ wr[(ky * 3 + kx) * W + wd]);
              if (dy == 0) { if (dx == 0) a00 += p; else a01 += p; }
              else         { if (dx == 0) a10 += p; else a11 += p; }
            }
          }
        }
      }
#pragma unroll
      for (int j = 0; j < 2 * W; j++) c[cy][j] = f[j];
    }
    int dot = K - 2 * min(min(a00, a01), min(a10, a11));
    float f = (float)dot;
    long idx = CL ? (((long)n * PH * PH + py * PH + px) * CO + co)
                  : (((long)n * CO + co) * PH * PH + (py * PH + px));
    out[idx] = dot >= 0 ? f : alpha * f;
  }
}

// 4-col streaming variant (conv3, W=4): no carry (carry would need ~160
// VGPR: wr alone is 72). Re-reads the 2 overlap cols: per px per cy 4 cols =
// 16 u64 = 4 b128 -> 96 b128/wave -> 27.6k LDS cyc/CU < 41.5k VALU => still
// VALU-bound. Live ~115 VGPR under the 170 budget.
template <int W, int IH, int PH, int CHUNK, bool CL>
__global__ __attribute__((amdgpu_flat_work_group_size(256, 256),
                          amdgpu_waves_per_eu(3, 4)))
void convp_str(const uint64_t* __restrict__ in, const uint64_t* __restrict__ wt,
               const float* __restrict__ cp, float* __restrict__ out, int CO) {
  __shared__ uint64_t sIn[10 * IH * W];
  int n = blockIdx.y;
  int cg = blockIdx.x / CHUNK, chunk = blockIdx.x % CHUNK;
  int t = threadIdx.x, lane = t & 63, slot = t >> 6;
  int r0 = chunk * 8;
  int nr = min(10, IH - r0);
  const uint64_t* src = in + ((long)n * IH + r0) * (IH * W);
  for (int i = t; i < nr * IH * W; i += 256) sIn[i] = src[i];
  int co = cg * 64 + lane;
  uint64_t wr[9 * W];
  const uint64_t* wg = wt + (long)co * (9 * W);
#pragma unroll
  for (int i = 0; i < 9 * W; i++) wr[i] = wg[i];
  __syncthreads();
  int py = chunk * 4 + slot;
  if (py >= PH) return;
  float alpha = cp[0];
  const int K = 9 * 64 * W;
  const uint64_t* base = &sIn[(2 * slot) * (IH * W)];  // local row = 2*slot+cy
#pragma unroll
  for (int px = 0; px < PH; px++) {
    int a00 = 0, a01 = 0, a10 = 0, a11 = 0;
#pragma unroll
    for (int cy = 0; cy < 4; cy++) {
      uint64_t f[4 * W];
      const uint64_t* fp = &base[(cy * IH + 2 * px) * W];
#pragma unroll
      for (int j = 0; j < 4 * W; j++) f[j] = fp[j];
#pragma unroll
      for (int col = 0; col < 4; col++) {
#pragma unroll
        for (int wd = 0; wd < W; wd++) {
          uint64_t v = f[col * W + wd];
#pragma unroll
          for (int dy = 0; dy < 2; dy++) {
            int ky = cy - dy;
            if (ky < 0 || ky > 2) continue;
#pragma unroll
            for (int dx = 0; dx < 2; dx++) {
              int kx = col - dx;
              if (kx < 0 || kx > 2) continue;
              int p = __popcll(v ^ wr[(ky * 3 + kx) * W + wd]);
              if (dy == 0) { if (dx == 0) a00 += p; else a01 += p; }
              else         { if (dx == 0) a10 += p; else a11 += p; }
            }
          }
        }
      }
    }
    int dot = K - 2 * min(min(a00, a01), min(a10, a11));
    float f = (float)dot;
    long idx = CL ? (((long)n * PH * PH + py * PH + px) * CO + co)
                  : (((long)n * CO + co) * PH * PH + (py * PH + px));
    out[idx] = dot >= 0 ? f : alpha * f;
  }
}

// ---------------- binary fc (with nonzero mask on activations) ----------------

// 2 rows per block (grid (4,64) = 256 blocks = 1/CU); weights transposed
// [wd][O] -> lane-coalesced 512B loads reused x2; nzc computed inline.
__global__ void fc_bin2(const uint64_t* __restrict__ xp, const uint64_t* __restrict__ wp_t,
                        const float* __restrict__ cp, float* __restrict__ out,
                        int O, int Wf) {
  __shared__ uint64_t xs[2][288], xz[2][288];
  int r0 = blockIdx.y * 2;
  for (int i = threadIdx.x; i < 2 * Wf; i += blockDim.x) {
    int rr = i / Wf, wd = i - rr * Wf;
    xs[rr][wd] = xp[(((long)(r0 + rr)) * Wf + wd) * 2];
    xz[rr][wd] = xp[(((long)(r0 + rr)) * Wf + wd) * 2 + 1];
  }
  __syncthreads();
  int o = blockIdx.x * blockDim.x + threadIdx.x;
  if (o >= O) return;
  int pc0 = 0, pc1 = 0, nz0 = 0, nz1 = 0;
  for (int wd = 0; wd < Wf; wd++) {
    uint64_t w = wp_t[(long)wd * O + o];
    uint64_t z0 = xz[0][wd], z1 = xz[1][wd];
    pc0 += __popcll((xs[0][wd] ^ w) & z0);
    pc1 += __popcll((xs[1][wd] ^ w) & z1);
    nz0 += __popcll(z0);
    nz1 += __popcll(z1);
  }
  float alpha = cp[0];
  int d0 = nz0 - 2 * pc0, d1 = nz1 - 2 * pc1;
  float f0 = (float)d0, f1 = (float)d1;
  out[(long)r0 * O + o] = d0 >= 0 ? f0 : alpha * f0;
  out[(long)(r0 + 1) * O + o] = d1 >= 0 ? f1 : alpha * f1;
}

__global__ void fc_bin_scale(const uint64_t* __restrict__ xp, const uint64_t* __restrict__ wp_t,
                             const float* __restrict__ cp, const float* __restrict__ scale,
                             float* __restrict__ out, int R, int O, int Wf) {
  int i = blockIdx.x * blockDim.x + threadIdx.x;
  if (i >= R * O) return;
  int o = i % O, r = i / O;
  int pc = 0, nzc = 0;
  for (int wd = 0; wd < Wf; wd++) {
    uint64_t nz = xp[((long)r * Wf + wd) * 2 + 1];
    pc += __popcll((xp[((long)r * Wf + wd) * 2] ^ wp_t[(long)wd * O + o]) & nz);
    nzc += __popcll(nz);
  }
  int dot = nzc - 2 * pc;
  float f = (float)dot;
  float alpha = cp[0];
  f = dot >= 0 ? f : alpha * f;
  out[i] = f * scale[0];
}

// ---------------- launch ----------------

extern "C" void kernel_launch(void* const* d_in, const int* in_sizes, int n_in,
                              void* d_out, int out_size, void* d_ws, size_t ws_size,
                              hipStream_t stream) {
  const float* x   = (const float*)d_in[0];
  const float* cg0 = (const float*)d_in[1];
  const float* cb0 = (const float*)d_in[2];
  const float* cw0 = (const float*)d_in[3];
  const float* cp0 = (const float*)d_in[4];
  const float* cg1 = (const float*)d_in[5];
  const float* cb1 = (const float*)d_in[6];
  const float* cw1 = (const float*)d_in[7];
  const float* cp1 = (const float*)d_in[8];
  const float* cg2 = (const float*)d_in[9];
  const float* cb2 = (const float*)d_in[10];
  const float* cw2 = (const float*)d_in[11];
  const float* cp2 = (const float*)d_in[12];
  const float* fg0 = (const float*)d_in[13];
  const float* fb0 = (const float*)d_in[14];
  const float* fw0 = (const float*)d_in[15];
  const float* fp0 = (const float*)d_in[16];
  const float* fg1 = (const float*)d_in[17];
  const float* fb1 = (const float*)d_in[18];
  const float* fw1 = (const float*)d_in[19];
  const float* fp1 = (const float*)d_in[20];
  const float* scl = (const float*)d_in[21];

  char* ws = (char*)d_ws;
  size_t off = 0;
  auto alloc = [&](size_t bytes) {
    size_t r = off;
    off += (bytes + 255) & ~(size_t)255;
    return r;
  };
  const int C0_OFF = 0, C1_OFF = 16, C2_OFF = 160, C3_OFF = 448, C4_OFF = 18944;
  const int NCH = 19968;

  double*   sums  = (double*)(ws + alloc((size_t)NCH * 2 * sizeof(double)));
  double2*  stats = (double2*)(ws + alloc((size_t)NCH * sizeof(double2)));
  uint64_t* rows0 = (uint64_t*)(ws + alloc(128L * 3 * 64 * 8));
  uint32_t* wm1   = (uint32_t*)(ws + alloc(128L * 4));
  float*    a1    = (float*)(ws + alloc(128L * 961 * 128 * 4));   // channel-last
  uint64_t* s1p   = (uint64_t*)(ws + alloc(128L * 961 * 2 * 8));
  uint64_t* w1p   = (uint64_t*)(ws + alloc(256L * 9 * 2 * 8));
  float*    a2    = (float*)(ws + alloc(128L * 196 * 256 * 4));   // channel-last
  uint64_t* s2p   = (uint64_t*)(ws + alloc(128L * 196 * 4 * 8));
  uint64_t* w2p   = (uint64_t*)(ws + alloc(512L * 9 * 4 * 8));
  float*    a3    = (float*)(ws + alloc(128L * 512 * 36 * 4));    // channel-major (reshape order)
  uint64_t* s3p   = (uint64_t*)(ws + alloc(128L * 288 * 2 * 8));
  uint64_t* w3p   = (uint64_t*)(ws + alloc(1024L * 288 * 8));     // transposed [288][1024]
  float*    f1    = (float*)(ws + alloc(128L * 1024 * 4));
  uint64_t* s4p   = (uint64_t*)(ws + alloc(128L * 16 * 2 * 8));
  uint64_t* w4p   = (uint64_t*)(ws + alloc(10L * 16 * 8));        // transposed [16][10]

  const int B = 256;

  zero_d<<<dim3(156), B, 0, stream>>>(sums, NCH * 2);

  // ---- block 0: BN(x) -> sign-bits -> conv1(popcount) -> pool -> prelu ----
  reduce_plane<<<dim3(3, 128), B, 0, stream>>>(x, sums + 2 * C0_OFF, 3, 4096);
  finalize_stats<<<1, 64, 0, stream>>>(sums + 2 * C0_OFF, stats + C0_OFF, 3, 524288.0);
  pack_bits_c1<<<dim3(6144), B, 0, stream>>>(x, stats + C0_OFF, cg0, cb0, rows0);
  pack_wc1<<<1, 128, 0, stream>>>(cw0, wm1);
  conv1_pool3<<<dim3(16, 128), B, 0, stream>>>(rows0, wm1, cp0, a1);

  // ---- block 1: BN(a1) -> pack -> conv2 -> pool -> prelu ----
  reduce_cl<<<dim3(2, 256), B, 0, stream>>>(a1, sums + 2 * C1_OFF, 128, 123008L);
  finalize_stats<<<1, 128, 0, stream>>>(sums + 2 * C1_OFF, stats + C1_OFF, 128, 123008.0);
  pack_cl<<<dim3(61504), B, 0, stream>>>(a1, stats + C1_OFF, cg1, cb1, s1p, 128, 246016L, 1);
  pack_wconv<<<dim3(18), B, 0, stream>>>(cw1, w1p, 256, 128, 2);
  // 4 co-groups x 4 py-chunks
  convp_carry<2, 31, 14, 4, true><<<dim3(16, 128), B, 0, stream>>>(s1p, w1p, cp1, a2, 256);

  // ---- block 2: BN(a2) -> pack -> conv3 -> pool -> prelu ----
  reduce_cl<<<dim3(4, 128), B, 0, stream>>>(a2, sums + 2 * C2_OFF, 256, 25088L);
  finalize_stats<<<1, 256, 0, stream>>>(sums + 2 * C2_OFF, stats + C2_OFF, 256, 25088.0);
  pack_cl<<<dim3(25088), B, 0, stream>>>(a2, stats + C2_OFF, cg2, cb2, s2p, 256, 100352L, 2);
  pack_wconv<<<dim3(72), B, 0, stream>>>(cw2, w2p, 512, 256, 4);
  // 8 co-groups x 2 py-chunks
  convp_str<4, 14, 6, 2, false><<<dim3(16, 128), B, 0, stream>>>(s2p, w2p, cp2, a3, 512);

  // ---- fc 0: BN1d -> sign @ sign(W).T -> prelu ----
  reduce_cols2<<<dim3(72, 8), B, 0, stream>>>(a3, sums + 2 * C3_OFF, 128, 18432, 16);
  finalize_stats<<<dim3(72), B, 0, stream>>>(sums + 2 * C3_OFF, stats + C3_OFF, 18432, 128.0);
  pack_nz<<<dim3(9216), B, 0, stream>>>(a3, stats + C3_OFF, fg0, fb0, s3p, 128, 18432);
  pack_wfc2_t<<<dim3(73728), B, 0, stream>>>(fw0, w3p, 1024, 18432);
  fc_bin2<<<dim3(4, 64), B, 0, stream>>>(s3p, w3p, fp0, f1, 1024, 288);

  // ---- fc 1: BN1d -> sign @ sign(W).T -> prelu -> scale ----
  reduce_cols2<<<dim3(4, 8), B, 0, stream>>>(f1, sums + 2 * C4_OFF, 128, 1024, 16);
  finalize_stats<<<dim3(4), B, 0, stream>>>(sums + 2 * C4_OFF, stats + C4_OFF, 1024, 128.0);
  pack_nz<<<dim3(512), B, 0, stream>>>(f1, stats + C4_OFF, fg1, fb1, s4p, 128, 1024);
  pack_wfc2_t<<<dim3(40), B, 0, stream>>>(fw1, w4p, 10, 1024);
  fc_bin_scale<<<dim3(5), B, 0, stream>>>(s4p, w4p, fp1, scl, (float*)d_out, 128, 10, 16);
}

// Round 4
// 551.671 us; speedup vs baseline: 1.2234x; 1.2205x over previous
//
#include <hip/hip_runtime.h>
#include <cstdint>
#include <cstddef>

#define BN_EPS 1e-5

// ---------------- reductions (fp64 for exact sign decisions) ----------------

__global__ void zero_d(double* p, int n) {
  int i = blockIdx.x * blockDim.x + threadIdx.x;
  if (i < n) p[i] = 0.0;
}

// one contiguous HW plane per block: grid (C, N)
__global__ void reduce_plane(const float* __restrict__ x, double* __restrict__ sums,
                             int C, int HW) {
  int c = blockIdx.x, n = blockIdx.y;
  const float* p = x + ((long)n * C + c) * HW;
  double s = 0.0, s2 = 0.0;
  for (int i = threadIdx.x; i < HW; i += blockDim.x) {
    double v = (double)p[i];
    s += v; s2 += v * v;
  }
  for (int o = 32; o > 0; o >>= 1) {
    s  += __shfl_down(s, o, 64);
    s2 += __shfl_down(s2, o, 64);
  }
  __shared__ double ls[4], ls2[4];
  int lane = threadIdx.x & 63, w = threadIdx.x >> 6;
  if (lane == 0) { ls[w] = s; ls2[w] = s2; }
  __syncthreads();
  if (threadIdx.x == 0) {
    double a = 0, b = 0;
    for (int i = 0; i < 4; i++) { a += ls[i]; b += ls2[i]; }
    atomicAdd(&sums[2 * c], a);
    atomicAdd(&sums[2 * c + 1], b);
  }
}

// channel-last reduce: x [rows][C]; grid (C/64, RB), block 256 (4 waves).
__global__ void reduce_cl(const float* __restrict__ x, double* __restrict__ sums,
                          int C, long rows) {
  int lane = threadIdx.x & 63, wv = threadIdx.x >> 6;
  int c = blockIdx.x * 64 + lane;
  double s = 0.0, s2 = 0.0;
  for (long r = blockIdx.y * 4 + wv; r < rows; r += (long)gridDim.y * 4) {
    double v = (double)x[r * C + c];
    s += v; s2 += v * v;
  }
  __shared__ double ls[4][64], ls2[4][64];
  ls[wv][lane] = s; ls2[wv][lane] = s2;
  __syncthreads();
  if (threadIdx.x < 64) {
    double a = ls[0][lane] + ls[1][lane] + ls[2][lane] + ls[3][lane];
    double b = ls2[0][lane] + ls2[1][lane] + ls2[2][lane] + ls2[3][lane];
    atomicAdd(&sums[2 * c], a);
    atomicAdd(&sums[2 * c + 1], b);
  }
}

// row-split per-feature reduce of R x F (F % 256 == 0); grid (F/256, RB).
__global__ void reduce_cols2(const float* __restrict__ x, double* __restrict__ sums,
                             int R, int F, int RS) {
  int f = blockIdx.x * blockDim.x + threadIdx.x;
  int r0 = blockIdx.y * RS, r1 = min(r0 + RS, R);
  double s = 0.0, s2 = 0.0;
  for (int r = r0; r < r1; r++) {
    double v = (double)x[(long)r * F + f];
    s += v; s2 += v * v;
  }
  atomicAdd(&sums[2 * f], s);
  atomicAdd(&sums[2 * f + 1], s2);
}

__global__ void finalize_stats(const double* __restrict__ sums, double2* __restrict__ st,
                               int C, double cnt) {
  int c = blockIdx.x * blockDim.x + threadIdx.x;
  if (c >= C) return;
  double m = sums[2 * c] / cnt;
  double v = sums[2 * c + 1] / cnt - m * m;
  st[c] = make_double2(m, 1.0 / sqrt(v + BN_EPS));
}

// ---------------- ballot-based sign/pack kernels ----------------

__global__ void pack_bits_c1(const float* __restrict__ x, const double2* __restrict__ st,
                             const float* __restrict__ g, const float* __restrict__ b,
                             uint64_t* __restrict__ rows) {
  int wid = blockIdx.x * 4 + (threadIdx.x >> 6);
  int lane = threadIdx.x & 63;
  int n = wid / 192, rem = wid % 192;
  int ci = rem >> 6, y = rem & 63;
  double2 s = st[ci];
  float xv = x[(((long)n * 3 + ci) * 64 + y) * 64 + lane];
  float xn = (float)(((double)xv - s.x) * s.y) * g[ci] + b[ci];
  uint64_t m = __ballot(xn > 0.f);
  if (lane == 0) rows[wid] = m;
}

__global__ void pack_wc1(const float* __restrict__ w, uint32_t* __restrict__ wm) {
  int co = threadIdx.x;
  uint32_t m = 0;
  for (int j = 0; j < 27; j++) m |= (uint32_t)(w[co * 27 + j] > 0.f) << j;
  wm[co] = m;
}

__global__ void pack_cl(const float* __restrict__ acl, const double2* __restrict__ st,
                        const float* __restrict__ g, const float* __restrict__ b,
                        uint64_t* __restrict__ out, int C, long nwords, int lw) {
  long wid = (long)blockIdx.x * 4 + (threadIdx.x >> 6);
  if (wid >= nwords) return;
  int lane = threadIdx.x & 63;
  long row = wid >> lw;
  int w = (int)(wid & ((1 << lw) - 1));
  int c = w * 64 + lane;
  double2 s = st[c];
  float xv = acl[row * C + c];
  float xn = (float)(((double)xv - s.x) * s.y) * g[c] + b[c];
  uint64_t m = __ballot(xn > 0.f);
  if (lane == 0) out[wid] = m;
}

__global__ void pack_wconv(const float* __restrict__ w, uint64_t* __restrict__ out,
                           int CO, int CI, int W) {
  int i = blockIdx.x * blockDim.x + threadIdx.x;
  int total = CO * 9 * W;
  if (i >= total) return;
  int wd = i % W;
  int t = i / W;
  int tap = t % 9, co = t / 9;
  uint64_t bits = 0;
  for (int k = 0; k < 64; k++) {
    int ci = wd * 64 + k;
    bits |= (uint64_t)(w[((long)co * CI + ci) * 9 + tap] > 0.f) << k;
  }
  out[i] = bits;
}

// pack sign + nonzero masks. NO per-row atomic (R2: 288-way same-address fp64
// atomic contention serialized this to 93us). nzc recomputed inline in fc.
__global__ void pack_nz(const float* __restrict__ x, const double2* __restrict__ st,
                        const float* __restrict__ g, const float* __restrict__ b,
                        uint64_t* __restrict__ out, int R, int F) {
  int Wf = F >> 6;
  long wid = (long)blockIdx.x * 4 + (threadIdx.x >> 6);
  if (wid >= (long)R * Wf) return;
  int lane = threadIdx.x & 63;
  long r = wid / Wf;
  int w = (int)(wid % Wf);
  int f = w * 64 + lane;
  double2 s = st[f];
  double d = (double)x[r * F + f] - s.x;  // exact for lattice values
  float xn = (float)(d * s.y) * g[f] + b[f];
  uint64_t sm = __ballot(xn > 0.f);
  uint64_t nm = __ballot(d != 0.0);
  if (lane == 0) { out[2 * wid] = sm; out[2 * wid + 1] = nm; }
}

// transposed weight pack: out [wd][O] so fc weight loads are lane-coalesced
__global__ void pack_wfc2_t(const float* __restrict__ w, uint64_t* __restrict__ out,
                            int O, int F) {
  int Wf = F >> 6;
  long wid = (long)blockIdx.x * 4 + (threadIdx.x >> 6);
  if (wid >= (long)O * Wf) return;
  int lane = threadIdx.x & 63;
  long o = wid / Wf;
  int wd = (int)(wid % Wf);
  uint64_t m = __ballot(w[o * F + wd * 64 + lane] > 0.f);
  if (lane == 0) out[(long)wd * O + o] = m;
}

// ---------------- fused conv + maxpool + prelu ----------------

// conv1 via 27-bit xnor-popcount; out channel-last [n][961][128]
__global__ __launch_bounds__(256) void conv1_pool3(const uint64_t* __restrict__ rows,
                                                   const uint32_t* __restrict__ wm,
                                                   const float* __restrict__ cp,
                                                   float* __restrict__ out) {
  __shared__ uint64_t rL[192];
  __shared__ uint32_t wL[128];
  __shared__ uint32_t mL[61 * 4];
  int n = blockIdx.y, chunk = blockIdx.x, t = threadIdx.x;
  if (t < 192) rL[t] = rows[n * 192 + t];
  if (t < 128) wL[t] = wm[t];
  __syncthreads();
  if (t < 244) {
    int pl = t >> 2, quad = t & 3;
    int pos = chunk * 61 + pl;
    if (pos < 961) {
      int py = pos / 31, px = pos - py * 31;
      int cy = 2 * py + (quad >> 1), cx = 2 * px + (quad & 1);
      uint32_t m = 0;
#pragma unroll
      for (int ci = 0; ci < 3; ci++)
#pragma unroll
        for (int ky = 0; ky < 3; ky++)
          m |= (uint32_t)((rL[ci * 64 + cy + ky] >> cx) & 7) << (ci * 9 + ky * 3);
      mL[pl * 4 + quad] = m;
    }
  }
  __syncthreads();
  int co = t & 127, slot = t >> 7;
  float alpha = cp[0];
  uint32_t w = wL[co];
  for (int i = slot; i < 61; i += 2) {
    int pos = chunk * 61 + i;
    if (pos >= 961) break;
    int p0 = __popc(mL[4 * i] ^ w);
    int p1 = __popc(mL[4 * i + 1] ^ w);
    int p2 = __popc(mL[4 * i + 2] ^ w);
    int p3 = __popc(mL[4 * i + 3] ^ w);
    int dot = 27 - 2 * min(min(p0, p1), min(p2, p3));
    float f = (float)dot;
    out[((long)n * 961 + pos) * 128 + co] = dot >= 0 ? f : alpha * f;
  }
}

// R3 post-mortem: u64 ARRAYS (wr[36], f[16]) were demoted to SCRATCH
// (convp_str: 682 MB HBM traffic/dispatch, 194us, VGPR_Count=84 << live set).
// R4: NO arrays anywhere in the conv kernels — every weight/carry word is a
// NAMED scalar. To fit the named live set in arch VGPRs, input-channel words
// are split across HALF-WAVES: lane L and L+32 share co but hold different
// wd words; quadrant partials are combined with __shfl_xor(.,32).
// waves_per_eu(4,6): budget 512/6=85 VGPR >= ~62 live, floor 4 waves/EU.

// one tap-row applied to 4 window columns (x0..x3) for quadrant pair (aL,aR)
#define ROW6(aL, aR, x0, x1, x2, x3, wa, wb, wc)                                \
  aL += __popcll((x0) ^ (wa)) + __popcll((x1) ^ (wb)) + __popcll((x2) ^ (wc)); \
  aR += __popcll((x1) ^ (wa)) + __popcll((x2) ^ (wb)) + __popcll((x3) ^ (wc));

// conv2: in s1p [n][31][31][2], wt w1p [256][9][2], out a2 CL [n][196][256].
// Half h holds wd=h (channels 64h..64h+63): 9 named weight u64.
// 2-column carry as 8 named u64, ping-pong macro (no copy movs).
#define CSTEP(C00, C01, C10, C11, C20, C21, C30, C31,                     \
              D00, D01, D10, D11, D20, D21, D30, D31)                     \
  {                                                                       \
    D00 = rq[0];   D01 = rq[2];                                           \
    D10 = rq[62];  D11 = rq[64];                                          \
    D20 = rq[124]; D21 = rq[126];                                         \
    D30 = rq[186]; D31 = rq[188];                                         \
    int a00 = 0, a01 = 0, a10 = 0, a11 = 0;                               \
    ROW6(a00, a01, C00, C01, D00, D01, w0, w1, w2)                        \
    ROW6(a00, a01, C10, C11, D10, D11, w3, w4, w5)                        \
    ROW6(a10, a11, C10, C11, D10, D11, w0, w1, w2)                        \
    ROW6(a00, a01, C20, C21, D20, D21, w6, w7, w8)                        \
    ROW6(a10, a11, C20, C21, D20, D21, w3, w4, w5)                        \
    ROW6(a10, a11, C30, C31, D30, D31, w6, w7, w8)                        \
    int t00 = a00 + __shfl_xor(a00, 32);                                  \
    int t01 = a01 + __shfl_xor(a01, 32);                                  \
    int t10 = a10 + __shfl_xor(a10, 32);                                  \
    int t11 = a11 + __shfl_xor(a11, 32);                                  \
    if (h == 0) {                                                         \
      int dot = 1152 - 2 * min(min(t00, t01), min(t10, t11));             \
      float ff = (float)dot;                                              \
      *outp = dot >= 0 ? ff : alpha * ff;                                 \
    }                                                                     \
    rq += 4; outp += 256;                                                 \
  }

__global__ __attribute__((amdgpu_flat_work_group_size(256, 256),
                          amdgpu_waves_per_eu(4, 6)))
void convs2(const uint64_t* __restrict__ in, const uint64_t* __restrict__ wt,
            const float* __restrict__ cp, float* __restrict__ out) {
  __shared__ uint64_t sIn[10 * 31 * 2];
  int n = blockIdx.y;
  int cg = blockIdx.x >> 2, chunk = blockIdx.x & 3;
  int t = threadIdx.x, lane = t & 63, slot = t >> 6;
  int r0 = chunk * 8;
  int nr = min(10, 31 - r0);
  const uint64_t* src = in + ((long)n * 31 + r0) * 62;
  for (int i = t; i < nr * 62; i += 256) sIn[i] = src[i];
  int h = lane >> 5;
  int co = cg * 32 + (lane & 31);
  const uint64_t* wg = wt + co * 18 + h;
  uint64_t w0 = wg[0],  w1 = wg[2],  w2 = wg[4];
  uint64_t w3 = wg[6],  w4 = wg[8],  w5 = wg[10];
  uint64_t w6 = wg[12], w7 = wg[14], w8 = wg[16];
  __syncthreads();
  int py = chunk * 4 + slot;
  if (py >= 14) return;
  float alpha = cp[0];
  const uint64_t* rp = sIn + (2 * slot) * 62 + h;
  uint64_t c00 = rp[0],   c01 = rp[2];
  uint64_t c10 = rp[62],  c11 = rp[64];
  uint64_t c20 = rp[124], c21 = rp[126];
  uint64_t c30 = rp[186], c31 = rp[188];
  uint64_t d00, d01, d10, d11, d20, d21, d30, d31;
  const uint64_t* rq = rp + 4;
  float* outp = out + ((long)n * 196 + py * 14) * 256 + co;
  for (int px2 = 0; px2 < 7; px2++) {
    CSTEP(c00, c01, c10, c11, c20, c21, c30, c31,
          d00, d01, d10, d11, d20, d21, d30, d31)
    CSTEP(d00, d01, d10, d11, d20, d21, d30, d31,
          c00, c01, c10, c11, c20, c21, c30, c31)
  }
}

// conv3: in s2p [n][14][14][4], wt w2p [512][9][4], out a3 CM [n][512][36].
// Half h holds wd pair {2h, 2h+1} (channels 128h..128h+127): 9 named
// ulonglong2 weights; window words read as ds_read_b128 pairs, consumed
// immediately (peak transient = 4 pairs).
#define TAP2(acc, P, wa, wb) acc += __popcll((P).x ^ (wa)) + __popcll((P).y ^ (wb));
#define ROWT(aL, aR, pA, pB, pC, pD, WX, WY, WZ)                \
  TAP2(aL, pA, WX.x, WX.y) TAP2(aL, pB, WY.x, WY.y)             \
  TAP2(aL, pC, WZ.x, WZ.y)                                      \
  TAP2(aR, pB, WX.x, WX.y) TAP2(aR, pC, WY.x, WY.y)             \
  TAP2(aR, pD, WZ.x, WZ.y)

__global__ __attribute__((amdgpu_flat_work_group_size(256, 256),
                          amdgpu_waves_per_eu(4, 6)))
void convs3(const uint64_t* __restrict__ in, const uint64_t* __restrict__ wt,
            const float* __restrict__ cp, float* __restrict__ out) {
  __shared__ uint64_t sIn[14 * 14 * 4];
  int n = blockIdx.y, cg = blockIdx.x;
  int t = threadIdx.x, lane = t & 63, slot = t >> 6;
  const uint64_t* src = in + (long)n * 784;
  for (int i = t; i < 784; i += 256) sIn[i] = src[i];
  int h = lane >> 5;
  int co = cg * 32 + (lane & 31);
  const uint64_t* wg = wt + co * 36 + 2 * h;
  ulonglong2 W0 = *(const ulonglong2*)(wg + 0);
  ulonglong2 W1 = *(const ulonglong2*)(wg + 4);
  ulonglong2 W2 = *(const ulonglong2*)(wg + 8);
  ulonglong2 W3 = *(const ulonglong2*)(wg + 12);
  ulonglong2 W4 = *(const ulonglong2*)(wg + 16);
  ulonglong2 W5 = *(const ulonglong2*)(wg + 20);
  ulonglong2 W6 = *(const ulonglong2*)(wg + 24);
  ulonglong2 W7 = *(const ulonglong2*)(wg + 28);
  ulonglong2 W8 = *(const ulonglong2*)(wg + 32);
  __syncthreads();
  float alpha = cp[0];
  float* outb = out + ((long)n * 512 + co) * 36;
#pragma unroll
  for (int k = 0; k < 9; k++) {
    int pos = slot + 4 * k;  // 0..35
    int py = pos / 6, px = pos - py * 6;
    const uint64_t* q = sIn + ((2 * py) * 14 + 2 * px) * 4 + 2 * h;
    int a00 = 0, a01 = 0, a10 = 0, a11 = 0;
    {
      ulonglong2 p0 = *(const ulonglong2*)(q + 0);
      ulonglong2 p1 = *(const ulonglong2*)(q + 4);
      ulonglong2 p2 = *(const ulonglong2*)(q + 8);
      ulonglong2 p3 = *(const ulonglong2*)(q + 12);
      ROWT(a00, a01, p0, p1, p2, p3, W0, W1, W2)
    }
    {
      const uint64_t* q1 = q + 56;
      ulonglong2 p0 = *(const ulonglong2*)(q1 + 0);
      ulonglong2 p1 = *(const ulonglong2*)(q1 + 4);
      ulonglong2 p2 = *(const ulonglong2*)(q1 + 8);
      ulonglong2 p3 = *(const ulonglong2*)(q1 + 12);
      ROWT(a00, a01, p0, p1, p2, p3, W3, W4, W5)
      ROWT(a10, a11, p0, p1, p2, p3, W0, W1, W2)
    }
    {
      const uint64_t* q2 = q + 112;
      ulonglong2 p0 = *(const ulonglong2*)(q2 + 0);
      ulonglong2 p1 = *(const ulonglong2*)(q2 + 4);
      ulonglong2 p2 = *(const ulonglong2*)(q2 + 8);
      ulonglong2 p3 = *(const ulonglong2*)(q2 + 12);
      ROWT(a00, a01, p0, p1, p2, p3, W6, W7, W8)
      ROWT(a10, a11, p0, p1, p2, p3, W3, W4, W5)
    }
    {
      const uint64_t* q3 = q + 168;
      ulonglong2 p0 = *(const ulonglong2*)(q3 + 0);
      ulonglong2 p1 = *(const ulonglong2*)(q3 + 4);
      ulonglong2 p2 = *(const ulonglong2*)(q3 + 8);
      ulonglong2 p3 = *(const ulonglong2*)(q3 + 12);
      ROWT(a10, a11, p0, p1, p2, p3, W6, W7, W8)
    }
    int t00 = a00 + __shfl_xor(a00, 32);
    int t01 = a01 + __shfl_xor(a01, 32);
    int t10 = a10 + __shfl_xor(a10, 32);
    int t11 = a11 + __shfl_xor(a11, 32);
    if (h == 0) {
      int dot = 2304 - 2 * min(min(t00, t01), min(t10, t11));
      float ff = (float)dot;
      outb[pos] = dot >= 0 ? ff : alpha * ff;
    }
  }
}

// ---------------- binary fc (with nonzero mask on activations) ----------------

// 2 rows per block; weights transposed [wd][O] -> lane-coalesced loads
// reused x2; nzc computed inline.
__global__ void fc_bin2(const uint64_t* __restrict__ xp, const uint64_t* __restrict__ wp_t,
                        const float* __restrict__ cp, float* __restrict__ out,
                        int O, int Wf) {
  __shared__ uint64_t xs[2][288], xz[2][288];
  int r0 = blockIdx.y * 2;
  for (int i = threadIdx.x; i < 2 * Wf; i += blockDim.x) {
    int rr = i / Wf, wd = i - rr * Wf;
    xs[rr][wd] = xp[(((long)(r0 + rr)) * Wf + wd) * 2];
    xz[rr][wd] = xp[(((long)(r0 + rr)) * Wf + wd) * 2 + 1];
  }
  __syncthreads();
  int o = blockIdx.x * blockDim.x + threadIdx.x;
  if (o >= O) return;
  int pc0 = 0, pc1 = 0, nz0 = 0, nz1 = 0;
  for (int wd = 0; wd < Wf; wd++) {
    uint64_t w = wp_t[(long)wd * O + o];
    uint64_t z0 = xz[0][wd], z1 = xz[1][wd];
    pc0 += __popcll((xs[0][wd] ^ w) & z0);
    pc1 += __popcll((xs[1][wd] ^ w) & z1);
    nz0 += __popcll(z0);
    nz1 += __popcll(z1);
  }
  float alpha = cp[0];
  int d0 = nz0 - 2 * pc0, d1 = nz1 - 2 * pc1;
  float f0 = (float)d0, f1 = (float)d1;
  out[(long)r0 * O + o] = d0 >= 0 ? f0 : alpha * f0;
  out[(long)(r0 + 1) * O + o] = d1 >= 0 ? f1 : alpha * f1;
}

__global__ void fc_bin_scale(const uint64_t* __restrict__ xp, const uint64_t* __restrict__ wp_t,
                             const float* __restrict__ cp, const float* __restrict__ scale,
                             float* __restrict__ out, int R, int O, int Wf) {
  int i = blockIdx.x * blockDim.x + threadIdx.x;
  if (i >= R * O) return;
  int o = i % O, r = i / O;
  int pc = 0, nzc = 0;
  for (int wd = 0; wd < Wf; wd++) {
    uint64_t nz = xp[((long)r * Wf + wd) * 2 + 1];
    pc += __popcll((xp[((long)r * Wf + wd) * 2] ^ wp_t[(long)wd * O + o]) & nz);
    nzc += __popcll(nz);
  }
  int dot = nzc - 2 * pc;
  float f = (float)dot;
  float alpha = cp[0];
  f = dot >= 0 ? f : alpha * f;
  out[i] = f * scale[0];
}

// ---------------- launch ----------------

extern "C" void kernel_launch(void* const* d_in, const int* in_sizes, int n_in,
                              void* d_out, int out_size, void* d_ws, size_t ws_size,
                              hipStream_t stream) {
  const float* x   = (const float*)d_in[0];
  const float* cg0 = (const float*)d_in[1];
  const float* cb0 = (const float*)d_in[2];
  const float* cw0 = (const float*)d_in[3];
  const float* cp0 = (const float*)d_in[4];
  const float* cg1 = (const float*)d_in[5];
  const float* cb1 = (const float*)d_in[6];
  const float* cw1 = (const float*)d_in[7];
  const float* cp1 = (const float*)d_in[8];
  const float* cg2 = (const float*)d_in[9];
  const float* cb2 = (const float*)d_in[10];
  const float* cw2 = (const float*)d_in[11];
  const float* cp2 = (const float*)d_in[12];
  const float* fg0 = (const float*)d_in[13];
  const float* fb0 = (const float*)d_in[14];
  const float* fw0 = (const float*)d_in[15];
  const float* fp0 = (const float*)d_in[16];
  const float* fg1 = (const float*)d_in[17];
  const float* fb1 = (const float*)d_in[18];
  const float* fw1 = (const float*)d_in[19];
  const float* fp1 = (const float*)d_in[20];
  const float* scl = (const float*)d_in[21];

  char* ws = (char*)d_ws;
  size_t off = 0;
  auto alloc = [&](size_t bytes) {
    size_t r = off;
    off += (bytes + 255) & ~(size_t)255;
    return r;
  };
  const int C0_OFF = 0, C1_OFF = 16, C2_OFF = 160, C3_OFF = 448, C4_OFF = 18944;
  const int NCH = 19968;

  double*   sums  = (double*)(ws + alloc((size_t)NCH * 2 * sizeof(double)));
  double2*  stats = (double2*)(ws + alloc((size_t)NCH * sizeof(double2)));
  uint64_t* rows0 = (uint64_t*)(ws + alloc(128L * 3 * 64 * 8));
  uint32_t* wm1   = (uint32_t*)(ws + alloc(128L * 4));
  float*    a1    = (float*)(ws + alloc(128L * 961 * 128 * 4));   // channel-last
  uint64_t* s1p   = (uint64_t*)(ws + alloc(128L * 961 * 2 * 8));
  uint64_t* w1p   = (uint64_t*)(ws + alloc(256L * 9 * 2 * 8));
  float*    a2    = (float*)(ws + alloc(128L * 196 * 256 * 4));   // channel-last
  uint64_t* s2p   = (uint64_t*)(ws + alloc(128L * 196 * 4 * 8));
  uint64_t* w2p   = (uint64_t*)(ws + alloc(512L * 9 * 4 * 8));
  float*    a3    = (float*)(ws + alloc(128L * 512 * 36 * 4));    // channel-major (reshape order)
  uint64_t* s3p   = (uint64_t*)(ws + alloc(128L * 288 * 2 * 8));
  uint64_t* w3p   = (uint64_t*)(ws + alloc(1024L * 288 * 8));     // transposed [288][1024]
  float*    f1    = (float*)(ws + alloc(128L * 1024 * 4));
  uint64_t* s4p   = (uint64_t*)(ws + alloc(128L * 16 * 2 * 8));
  uint64_t* w4p   = (uint64_t*)(ws + alloc(10L * 16 * 8));        // transposed [16][10]

  const int B = 256;

  zero_d<<<dim3(156), B, 0, stream>>>(sums, NCH * 2);

  // ---- block 0: BN(x) -> sign-bits -> conv1(popcount) -> pool -> prelu ----
  reduce_plane<<<dim3(3, 128), B, 0, stream>>>(x, sums + 2 * C0_OFF, 3, 4096);
  finalize_stats<<<1, 64, 0, stream>>>(sums + 2 * C0_OFF, stats + C0_OFF, 3, 524288.0);
  pack_bits_c1<<<dim3(6144), B, 0, stream>>>(x, stats + C0_OFF, cg0, cb0, rows0);
  pack_wc1<<<1, 128, 0, stream>>>(cw0, wm1);
  conv1_pool3<<<dim3(16, 128), B, 0, stream>>>(rows0, wm1, cp0, a1);

  // ---- block 1: BN(a1) -> pack -> conv2 -> pool -> prelu ----
  reduce_cl<<<dim3(2, 256), B, 0, stream>>>(a1, sums + 2 * C1_OFF, 128, 123008L);
  finalize_stats<<<1, 128, 0, stream>>>(sums + 2 * C1_OFF, stats + C1_OFF, 128, 123008.0);
  pack_cl<<<dim3(61504), B, 0, stream>>>(a1, stats + C1_OFF, cg1, cb1, s1p, 128, 246016L, 1);
  pack_wconv<<<dim3(18), B, 0, stream>>>(cw1, w1p, 256, 128, 2);
  // 8 co-groups (32 co each) x 4 py-chunks
  convs2<<<dim3(32, 128), B, 0, stream>>>(s1p, w1p, cp1, a2);

  // ---- block 2: BN(a2) -> pack -> conv3 -> pool -> prelu ----
  reduce_cl<<<dim3(4, 128), B, 0, stream>>>(a2, sums + 2 * C2_OFF, 256, 25088L);
  finalize_stats<<<1, 256, 0, stream>>>(sums + 2 * C2_OFF, stats + C2_OFF, 256, 25088.0);
  pack_cl<<<dim3(25088), B, 0, stream>>>(a2, stats + C2_OFF, cg2, cb2, s2p, 256, 100352L, 2);
  pack_wconv<<<dim3(72), B, 0, stream>>>(cw2, w2p, 512, 256, 4);
  // 16 co-groups (32 co each)
  convs3<<<dim3(16, 128), B, 0, stream>>>(s2p, w2p, cp2, a3);

  // ---- fc 0: BN1d -> sign @ sign(W).T -> prelu ----
  reduce_cols2<<<dim3(72, 8), B, 0, stream>>>(a3, sums + 2 * C3_OFF, 128, 18432, 16);
  finalize_stats<<<dim3(72), B, 0, stream>>>(sums + 2 * C3_OFF, stats + C3_OFF, 18432, 128.0);
  pack_nz<<<dim3(9216), B, 0, stream>>>(a3, stats + C3_OFF, fg0, fb0, s3p, 128, 18432);
  pack_wfc2_t<<<dim3(73728), B, 0, stream>>>(fw0, w3p, 1024, 18432);
  fc_bin2<<<dim3(4, 64), B, 0, stream>>>(s3p, w3p, fp0, f1, 1024, 288);

  // ---- fc 1: BN1d -> sign @ sign(W).T -> prelu -> scale ----
  reduce_cols2<<<dim3(4, 8), B, 0, stream>>>(f1, sums + 2 * C4_OFF, 128, 1024, 16);
  finalize_stats<<<dim3(4), B, 0, stream>>>(sums + 2 * C4_OFF, stats + C4_OFF, 1024, 128.0);
  pack_nz<<<dim3(512), B, 0, stream>>>(f1, stats + C4_OFF, fg1, fb1, s4p, 128, 1024);
  pack_wfc2_t<<<dim3(40), B, 0, stream>>>(fw1, w4p, 10, 1024);
  fc_bin_scale<<<dim3(5), B, 0, stream>>>(s4p, w4p, fp1, scl, (float*)d_out, 128, 10, 16);
}